// Round 2
// 775.835 us; speedup vs baseline: 1.0127x; 1.0127x over previous
//
#include <hip/hip_runtime.h>
#include <math.h>

#define DIM    256
#define K_EMB  1024
#define HW     4096
#define CHW    1048576
#define N_TOK  65536
#define NELEM  16777216

// d_out float offsets
#define OUT_LOSS 0
#define OUT_ZQ   1
#define OUT_PERP 16777217
#define OUT_MENC 16777218LL
#define OUT_IDX  83886082

#define TAU  1.5e-4f  // flag margin (proven r4): |s_mfma - s_np| <= TAU/2

// Scratch parked in the LAST 320 min_encodings rows (rows 65216..65535), which
// are written only by menc_tail AFTER refine. All other menc rows are written
// provisionally by vq_mfma and patched by refine.
// Offsets are floats from scr = out + OUT_MENC. abs float idx = 16777218 + off,
// so off ≡ 2 (mod 4) gives a 16B-aligned absolute address.
#define TAIL_ROW0  65216
#define FLAGS_OFF  66781184LL   // 65536 ints   (= row 65216 * 1024)
#define FBS_OFF    66846720LL   // 65536 floats (= row 65280 * 1024)
#define EH_OFF     66912258LL   // 1024x256 bf16 (512KB); ≡2 mod 4 -> 16B-aligned

typedef short short8  __attribute__((ext_vector_type(8)));
typedef float floatx4 __attribute__((ext_vector_type(4)));
typedef float floatx2 __attribute__((ext_vector_type(2)));

__device__ __forceinline__ unsigned short f2bf(float f) {  // RNE fp32->bf16
    unsigned int u = __float_as_uint(f);
    return (unsigned short)((u + 0x7FFFu + ((u >> 16) & 1u)) >> 16);
}
__device__ __forceinline__ float bf2f(unsigned short h) {
    return __uint_as_float(((unsigned int)h) << 16);
}

// ---- numpy pairwise summation, exact replication for n=256 (serial form) ----
__device__ __forceinline__ float np_pair128(const float* p) {
    float r[8];
    #pragma unroll
    for (int j = 0; j < 8; ++j) r[j] = p[j];
    for (int i = 8; i < 128; i += 8)
        #pragma unroll
        for (int j = 0; j < 8; ++j) r[j] = __fadd_rn(r[j], p[i + j]);
    return __fadd_rn(__fadd_rn(__fadd_rn(r[0], r[1]), __fadd_rn(r[2], r[3])),
                     __fadd_rn(__fadd_rn(r[4], r[5]), __fadd_rn(r[6], r[7])));
}
__device__ __forceinline__ float np_pair256(const float* p) {
    return __fadd_rn(np_pair128(p), np_pair128(p + 128));
}

// fused prep: one token's z row -> bf16 split fragments (identical math to old prep_z)
__device__ __forceinline__ void build_frags(const float* __restrict__ zp, int quad, short8* a) {
    #pragma unroll
    for (int kc = 0; kc < 8; ++kc) {
        short8 vh, vl;
        #pragma unroll
        for (int u = 0; u < 8; ++u) {
            float v = __builtin_nontemporal_load(zp + (size_t)(kc * 32 + quad * 8 + u) * HW);
            unsigned short h = f2bf(v);
            vh[u] = (short)h;
            vl[u] = (short)f2bf(v - bf2f(h));
        }
        a[kc]     = vh;
        a[8 + kc] = vl;
    }
}

// ---------------- t2[k] (np-exact) + eh bf16 rows ----------------
__global__ void t2_np_kernel(const float* __restrict__ embed, float* __restrict__ t2,
                             unsigned short* __restrict__ Eh) {
    int k = blockIdx.x * 256 + threadIdx.x;
    if (k >= K_EMB) return;
    const float* e = embed + (size_t)k * DIM;
    float p[256];
    for (int c = 0; c < DIM; c += 4) {
        float4 v = *(const float4*)(e + c);
        p[c]     = __fmul_rn(v.x, v.x);
        p[c + 1] = __fmul_rn(v.y, v.y);
        p[c + 2] = __fmul_rn(v.z, v.z);
        p[c + 3] = __fmul_rn(v.w, v.w);
    }
    t2[k] = np_pair256(p);
    unsigned short* dst = Eh + (size_t)k * DIM;
    for (int c0 = 0; c0 < DIM; c0 += 8) {
        short8 vh;
        #pragma unroll
        for (int u = 0; u < 8; ++u) vh[u] = (short)f2bf(e[c0 + u]);
        *(short8*)(dst + c0) = vh;
    }
}

// ---------------- MFMA fast pass: fused z-prep + top-2 + flags + provisional one-hot rows ----------------
__launch_bounds__(256, 4)
__global__ void vq_mfma(const float* __restrict__ z,
                        const unsigned short* __restrict__ Eh,
                        const float* __restrict__ t2g,
                        float* __restrict__ out,
                        unsigned int* __restrict__ nflag,
                        int* __restrict__ flags,
                        float* __restrict__ fbs) {
    __shared__ unsigned short lds_b[32 * 264];        // 32 codes x 256 bf16, pad 8
    __shared__ float t2_lds[K_EMB];
    __shared__ int midx[64];

    const int tid  = threadIdx.x;
    const int lane = tid & 63;
    const int wv   = tid >> 6;
    const int l15  = lane & 15;
    const int quad = lane >> 4;
    const int m0   = blockIdx.x * 64;

    for (int i = tid; i < K_EMB; i += 256) t2_lds[i] = t2g[i];

    short8 a[16];
    {
        const int n = m0 + wv * 16 + l15;
        build_frags(z + (size_t)(n >> 12) * CHW + (n & 4095), quad, a);
    }

    float bs[4], ss[4]; int bk[4];
    #pragma unroll
    for (int r = 0; r < 4; ++r) { bs[r] = 3.4e38f; ss[r] = 3.4e38f; bk[r] = 0; }

    const int srow = tid >> 3;
    const int scol = (tid & 7) * 32;

    for (int it = 0; it < 32; ++it) {
        const int n0 = it * 32;
        __syncthreads();
        {
            const short8* g = (const short8*)(Eh + (size_t)(n0 + srow) * 256 + scol);
            short8* l = (short8*)(lds_b + srow * 264 + scol);
            short8 v0 = g[0], v1 = g[1], v2 = g[2], v3 = g[3];
            l[0] = v0; l[1] = v1; l[2] = v2; l[3] = v3;
        }
        __syncthreads();
        floatx4 acc0 = {0.f, 0.f, 0.f, 0.f};
        floatx4 acc1 = {0.f, 0.f, 0.f, 0.f};
        #pragma unroll
        for (int kc = 0; kc < 8; ++kc) {
            short8 b0 = *(const short8*)(lds_b + l15 * 264 + kc * 32 + quad * 8);
            short8 b1 = *(const short8*)(lds_b + (16 + l15) * 264 + kc * 32 + quad * 8);
            acc0 = __builtin_amdgcn_mfma_f32_16x16x32_bf16(a[kc],     b0, acc0, 0, 0, 0);
            acc1 = __builtin_amdgcn_mfma_f32_16x16x32_bf16(a[kc],     b1, acc1, 0, 0, 0);
            acc0 = __builtin_amdgcn_mfma_f32_16x16x32_bf16(a[8 + kc], b0, acc0, 0, 0, 0);
            acc1 = __builtin_amdgcn_mfma_f32_16x16x32_bf16(a[8 + kc], b1, acc1, 0, 0, 0);
        }
        float t20 = t2_lds[n0 + l15];
        float t21 = t2_lds[n0 + 16 + l15];
        #pragma unroll
        for (int r = 0; r < 4; ++r) {
            float s0 = fmaf(-2.0f, acc0[r], t20);
            if (s0 < bs[r]) { ss[r] = bs[r]; bs[r] = s0; bk[r] = n0 + l15; }
            else if (s0 < ss[r]) ss[r] = s0;
            float s1 = fmaf(-2.0f, acc1[r], t21);
            if (s1 < bs[r]) { ss[r] = bs[r]; bs[r] = s1; bk[r] = n0 + 16 + l15; }
            else if (s1 < ss[r]) ss[r] = s1;
        }
    }

    // merge top-2 across the 16 lanes of each quad (token = wv*16 + quad*4 + r)
    #pragma unroll
    for (int r = 0; r < 4; ++r) {
        for (int mo = 1; mo < 16; mo <<= 1) {
            float obs = __shfl_xor(bs[r], mo, 64);
            float oss = __shfl_xor(ss[r], mo, 64);
            int   obk = __shfl_xor(bk[r], mo, 64);
            if (obs < bs[r] || (obs == bs[r] && obk < bk[r])) {
                ss[r] = fminf(bs[r], oss); bs[r] = obs; bk[r] = obk;
            } else {
                ss[r] = fminf(ss[r], obs);
            }
        }
        if (l15 == 0) {
            int tl = wv * 16 + quad * 4 + r;
            out[OUT_IDX + m0 + tl] = (float)bk[r];
            midx[tl] = bk[r];
            if (ss[r] - bs[r] < TAU) {
                unsigned int slot = atomicAdd(nflag, 1u);
                flags[slot] = m0 + tl;
                fbs[slot]   = bs[r];
            }
        }
    }

    // provisional one-hot rows (non-temporal: keep Eh L2-resident).
    // blocks >= 1019 own tail rows (scratch region) -> written later by menc_tail.
    if (blockIdx.x < (TAIL_ROW0 / 64)) {
        __syncthreads();
        #pragma unroll 1
        for (int j = 0; j < 64; ++j) {
            const int id = midx[j];
            floatx2* dst = (floatx2*)(out + OUT_MENC + (size_t)(m0 + j) * K_EMB);
            int c0 = tid * 2;
            floatx2 v;  v.x  = (c0 == id)       ? 1.0f : 0.0f;  v.y  = (c0 + 1 == id)  ? 1.0f : 0.0f;
            __builtin_nontemporal_store(v, dst + tid);
            int c1 = c0 + 512;
            floatx2 w2; w2.x = (c1 == id)       ? 1.0f : 0.0f;  w2.y = (c1 + 1 == id)  ? 1.0f : 0.0f;
            __builtin_nontemporal_store(w2, dst + 256 + tid);
        }
    }
}

// ---------------- refine: recompute MFMA scores for flagged tokens (bit-identical),
// window TAU -> candidates -> np-exact fp64 check -> patch idx + one-hot row ----------------
__launch_bounds__(256)
__global__ void refine_mfma(const float* __restrict__ z, const float* __restrict__ embed,
                            const unsigned short* __restrict__ Eh,
                            const float* __restrict__ t2g, float* __restrict__ out,
                            const unsigned int* __restrict__ nflag,
                            const int* __restrict__ flags,
                            const float* __restrict__ fbs) {
    __shared__ unsigned short lds_b[32 * 264];
    __shared__ float t2_lds[K_EMB];
    __shared__ int   ftok[64];
    __shared__ float fbest[64];
    __shared__ int   ccnt[64];
    __shared__ int   clist[64][32];
    __shared__ float pp4[4][256];

    const int tid  = threadIdx.x;
    const int lane = tid & 63;
    const int wv   = tid >> 6;
    const int l15  = lane & 15;
    const int quad = lane >> 4;
    const int nf   = (int)*nflag;

    for (int i = tid; i < K_EMB; i += 256) t2_lds[i] = t2g[i];

    const int srow = tid >> 3;
    const int scol = (tid & 7) * 32;

    for (int base = blockIdx.x * 64; base < nf; base += gridDim.x * 64) {
        __syncthreads();
        if (tid < 64) {
            int ii  = base + tid;
            int src = (ii < nf) ? ii : base;   // dup a valid token into empty slots
            ftok[tid]  = flags[src];
            fbest[tid] = fbs[src];
            ccnt[tid]  = 0;
        }
        __syncthreads();

        short8 a[16];
        {
            const int n = ftok[wv * 16 + l15];
            build_frags(z + (size_t)(n >> 12) * CHW + (n & 4095), quad, a);
        }
        float ftb[4];
        #pragma unroll
        for (int r = 0; r < 4; ++r) ftb[r] = fbest[wv * 16 + quad * 4 + r] + TAU;

        for (int it = 0; it < 32; ++it) {
            const int n0 = it * 32;
            __syncthreads();
            {
                const short8* g = (const short8*)(Eh + (size_t)(n0 + srow) * 256 + scol);
                short8* l = (short8*)(lds_b + srow * 264 + scol);
                short8 v0 = g[0], v1 = g[1], v2 = g[2], v3 = g[3];
                l[0] = v0; l[1] = v1; l[2] = v2; l[3] = v3;
            }
            __syncthreads();
            floatx4 acc0 = {0.f, 0.f, 0.f, 0.f};
            floatx4 acc1 = {0.f, 0.f, 0.f, 0.f};
            #pragma unroll
            for (int kc = 0; kc < 8; ++kc) {
                short8 b0 = *(const short8*)(lds_b + l15 * 264 + kc * 32 + quad * 8);
                short8 b1 = *(const short8*)(lds_b + (16 + l15) * 264 + kc * 32 + quad * 8);
                acc0 = __builtin_amdgcn_mfma_f32_16x16x32_bf16(a[kc],     b0, acc0, 0, 0, 0);
                acc1 = __builtin_amdgcn_mfma_f32_16x16x32_bf16(a[kc],     b1, acc1, 0, 0, 0);
                acc0 = __builtin_amdgcn_mfma_f32_16x16x32_bf16(a[8 + kc], b0, acc0, 0, 0, 0);
                acc1 = __builtin_amdgcn_mfma_f32_16x16x32_bf16(a[8 + kc], b1, acc1, 0, 0, 0);
            }
            float t20 = t2_lds[n0 + l15];
            float t21 = t2_lds[n0 + 16 + l15];
            #pragma unroll
            for (int r = 0; r < 4; ++r) {
                const int trow = wv * 16 + quad * 4 + r;
                float s0 = fmaf(-2.0f, acc0[r], t20);
                if (s0 <= ftb[r]) {
                    int pos = atomicAdd(&ccnt[trow], 1);
                    if (pos < 32) clist[trow][pos] = n0 + l15;
                }
                float s1 = fmaf(-2.0f, acc1[r], t21);
                if (s1 <= ftb[r]) {
                    int pos = atomicAdd(&ccnt[trow], 1);
                    if (pos < 32) clist[trow][pos] = n0 + 16 + l15;
                }
            }
        }
        __syncthreads();

        // exact np phase: wave wv owns token slots wv*16 .. wv*16+15
        for (int j = wv * 16; j < wv * 16 + 16; ++j) {
            if (base + j >= nf) break;
            const int n = ftok[j];
            int cnt = ccnt[j]; if (cnt > 32) cnt = 32;

            const float* zt = z + (size_t)(n >> 12) * CHW + (n & 4095);
            double zd[4];
            #pragma unroll
            for (int u = 0; u < 4; ++u) {
                float v = zt[(size_t)(lane + u * 64) * HW];
                zd[u] = (double)v;
                pp4[wv][lane + u * 64] = __fmul_rn(v, v);
            }
            __asm__ volatile("s_waitcnt lgkmcnt(0)" ::: "memory");
            // numpy-pairwise t1: lanes 0..15 do the 8 strided accumulators per half
            float rj = 0.0f;
            if (lane < 16) {
                int jj = lane & 7, half = lane >> 3;
                const float* p = &pp4[wv][half * 128 + jj];
                rj = p[0];
                #pragma unroll
                for (int ii = 1; ii < 16; ++ii) rj = __fadd_rn(rj, p[ii * 8]);
            }
            float v0 = __shfl(rj, 0, 64), v1 = __shfl(rj, 1, 64), v2 = __shfl(rj, 2, 64), v3 = __shfl(rj, 3, 64);
            float v4 = __shfl(rj, 4, 64), v5 = __shfl(rj, 5, 64), v6 = __shfl(rj, 6, 64), v7 = __shfl(rj, 7, 64);
            float h0 = __fadd_rn(__fadd_rn(__fadd_rn(v0, v1), __fadd_rn(v2, v3)),
                                 __fadd_rn(__fadd_rn(v4, v5), __fadd_rn(v6, v7)));
            v0 = __shfl(rj,  8, 64); v1 = __shfl(rj,  9, 64); v2 = __shfl(rj, 10, 64); v3 = __shfl(rj, 11, 64);
            v4 = __shfl(rj, 12, 64); v5 = __shfl(rj, 13, 64); v6 = __shfl(rj, 14, 64); v7 = __shfl(rj, 15, 64);
            float h1 = __fadd_rn(__fadd_rn(__fadd_rn(v0, v1), __fadd_rn(v2, v3)),
                                 __fadd_rn(__fadd_rn(v4, v5), __fadd_rn(v6, v7)));
            const float t1 = __fadd_rn(h0, h1);

            float bd = 3.4e38f; int bkk = 1 << 30;
            for (int ci = 0; ci < cnt; ++ci) {
                int k = clist[j][ci];
                const float* e = embed + (size_t)k * DIM;
                double s = 0.0;
                #pragma unroll
                for (int u = 0; u < 4; ++u) s = fma(zd[u], (double)e[lane + u * 64], s);
                for (int mo = 1; mo < 64; mo <<= 1) s += __shfl_xor(s, mo, 64);
                float rho = (float)s;
                float d = __fadd_rn(__fadd_rn(t1, t2_lds[k]), -__fmul_rn(2.0f, rho));
                if (d < bd || (d == bd && k < bkk)) { bd = d; bkk = k; }
            }
            if (lane == 0) {
                int old = (int)out[OUT_IDX + n];
                if (bkk != old) {
                    out[OUT_IDX + n] = (float)bkk;
                    if (n < TAIL_ROW0) {     // patch provisional one-hot row
                        out[OUT_MENC + (size_t)n * K_EMB + old] = 0.0f;
                        out[OUT_MENC + (size_t)n * K_EMB + bkk] = 1.0f;
                    }
                }
            }
        }
    }
}

// ---------------- tail one-hot rows (over the scratch region), after refine ----------------
__global__ void menc_tail(float* __restrict__ out) {
    const int row = TAIL_ROW0 + blockIdx.x;           // 320 rows
    const int id  = (int)out[OUT_IDX + row];
    floatx2* dst = (floatx2*)(out + OUT_MENC + (size_t)row * K_EMB);
    int c0 = threadIdx.x * 2;
    floatx2 v;  v.x  = (c0 == id)      ? 1.0f : 0.0f;  v.y  = (c0 + 1 == id) ? 1.0f : 0.0f;
    dst[threadIdx.x] = v;
    int c1 = c0 + 512;
    floatx2 w;  w.x  = (c1 == id)      ? 1.0f : 0.0f;  w.y  = (c1 + 1 == id) ? 1.0f : 0.0f;
    dst[256 + threadIdx.x] = w;
}

// ---------------- z_q gather + NCHW store + loss + counts ----------------
__launch_bounds__(256)
__global__ void zq_loss_kernel(const float* __restrict__ z, const float* __restrict__ embed,
                               float* __restrict__ out, unsigned int* __restrict__ counts,
                               float* __restrict__ loss_sum) {
    const int tid = threadIdx.x;
    const int blk = blockIdx.x;
    const int b   = blk >> 7;
    const int h   = (blk >> 1) & 63;
    const int wh  = blk & 1;
    const int w   = tid & 31;
    const int cs  = tid >> 5;
    const int n   = blk * 32 + w;

    const int myk = (int)out[OUT_IDX + n];
    if (tid < 32) atomicAdd(&counts[myk], 1u);

    const float* erow = embed + (size_t)myk * DIM;
    const float* zt = z   + (size_t)b * CHW + h * 64 + wh * 32;
    float*       zq = out + OUT_ZQ + (size_t)b * CHW + h * 64 + wh * 32;
    float lsum = 0.0f;
    for (int c = cs; c < DIM; c += 8) {
        float v  = erow[c];
        float dz = v - zt[(size_t)c * HW + w];
        lsum = fmaf(dz, dz, lsum);
        zq[(size_t)c * HW + w] = v;
    }
    #pragma unroll
    for (int off = 32; off > 0; off >>= 1) lsum += __shfl_down(lsum, off, 64);
    if ((tid & 63) == 0) atomicAdd(loss_sum, lsum);
}

// ---------------- loss scale + perplexity ----------------
__global__ void finalize_kernel(const unsigned int* __restrict__ counts,
                                const float* __restrict__ loss_sum,
                                float* __restrict__ out) {
    __shared__ float red[256];
    int tid = threadIdx.x;
    float hsum = 0.0f;
    for (int k = tid; k < K_EMB; k += 256) {
        float p = (float)counts[k] * (1.0f / 65536.0f);
        hsum += p * logf(p + 1e-10f);
    }
    red[tid] = hsum;
    __syncthreads();
    for (int s = 128; s > 0; s >>= 1) {
        if (tid < s) red[tid] += red[tid + s];
        __syncthreads();
    }
    if (tid == 0) {
        out[OUT_PERP] = expf(-red[0]);
        out[OUT_LOSS] = loss_sum[0] * 1.25f * (1.0f / (float)NELEM);
    }
}

extern "C" void kernel_launch(void* const* d_in, const int* in_sizes, int n_in,
                              void* d_out, int out_size, void* d_ws, size_t ws_size,
                              hipStream_t stream) {
    const float* z     = (const float*)d_in[0];
    const float* embed = (const float*)d_in[1];
    float* out = (float*)d_out;

    unsigned int* counts = (unsigned int*)d_ws;                  // 1024 * u32
    float* loss_sum      = (float*)((char*)d_ws + 4096);
    unsigned int* nflag  = (unsigned int*)((char*)d_ws + 4100);
    float* t2g           = (float*)((char*)d_ws + 8192);         // 1024 floats

    float* scr = out + OUT_MENC;                                 // scratch in min_enc tail
    int*            fl = (int*)(scr + FLAGS_OFF);
    float*          fb = (float*)(scr + FBS_OFF);
    unsigned short* Eh = (unsigned short*)(scr + EH_OFF);

    (void)hipMemsetAsync(d_ws, 0, 4104, stream);
    t2_np_kernel   <<<dim3(4),    dim3(256), 0, stream>>>(embed, t2g, Eh);
    vq_mfma        <<<dim3(1024), dim3(256), 0, stream>>>(z, Eh, t2g, out, nflag, fl, fb);
    refine_mfma    <<<dim3(128),  dim3(256), 0, stream>>>(z, embed, Eh, t2g, out, nflag, fl, fb);
    menc_tail      <<<dim3(320),  dim3(256), 0, stream>>>(out);
    zq_loss_kernel <<<dim3(2048), dim3(256), 0, stream>>>(z, embed, out, counts, loss_sum);
    finalize_kernel<<<dim3(1),    dim3(256), 0, stream>>>(counts, loss_sum, out);
}

// Round 4
// 774.076 us; speedup vs baseline: 1.0150x; 1.0023x over previous
//
#include <hip/hip_runtime.h>
#include <math.h>

#define DIM    256
#define K_EMB  1024
#define HW     4096
#define CHW    1048576
#define N_TOK  65536
#define NELEM  16777216

// d_out float offsets
#define OUT_LOSS 0
#define OUT_ZQ   1
#define OUT_PERP 16777217
#define OUT_MENC 16777218LL
#define OUT_IDX  83886082

#define TAU  1.5e-4f  // flag margin (proven r4): |s_mfma - s_np| <= TAU/2

// Scratch parked in the LAST 320 min_encodings rows (rows 65216..65535), which
// are written only by menc_tail AFTER refine. All other menc rows are written
// provisionally by vq_mfma and patched by refine.
#define TAIL_ROW0  65216
#define FLAGS_OFF  66781184LL   // 65536 ints   (= row 65216 * 1024)
#define FBS_OFF    66846720LL   // 65536 floats (= row 65280 * 1024)
#define EH_OFF     66912258LL   // 1024x256 bf16 (512KB); ≡2 mod 4 -> 16B-aligned

typedef short short8  __attribute__((ext_vector_type(8)));
typedef float floatx4 __attribute__((ext_vector_type(4)));
typedef float floatx2 __attribute__((ext_vector_type(2)));

__device__ __forceinline__ unsigned short f2bf(float f) {  // RNE fp32->bf16
    unsigned int u = __float_as_uint(f);
    return (unsigned short)((u + 0x7FFFu + ((u >> 16) & 1u)) >> 16);
}
__device__ __forceinline__ float bf2f(unsigned short h) {
    return __uint_as_float(((unsigned int)h) << 16);
}

// ---- numpy pairwise summation, exact replication for n=256 (serial form) ----
__device__ __forceinline__ float np_pair128(const float* p) {
    float r[8];
    #pragma unroll
    for (int j = 0; j < 8; ++j) r[j] = p[j];
    for (int i = 8; i < 128; i += 8)
        #pragma unroll
        for (int j = 0; j < 8; ++j) r[j] = __fadd_rn(r[j], p[i + j]);
    return __fadd_rn(__fadd_rn(__fadd_rn(r[0], r[1]), __fadd_rn(r[2], r[3])),
                     __fadd_rn(__fadd_rn(r[4], r[5]), __fadd_rn(r[6], r[7])));
}
__device__ __forceinline__ float np_pair256(const float* p) {
    return __fadd_rn(np_pair128(p), np_pair128(p + 128));
}

// fused prep: one token's z row -> bf16 split fragments
__device__ __forceinline__ void build_frags(const float* __restrict__ zp, int quad, short8* a) {
    #pragma unroll
    for (int kc = 0; kc < 8; ++kc) {
        short8 vh, vl;
        #pragma unroll
        for (int u = 0; u < 8; ++u) {
            float v = __builtin_nontemporal_load(zp + (size_t)(kc * 32 + quad * 8 + u) * HW);
            unsigned short h = f2bf(v);
            vh[u] = (short)h;
            vl[u] = (short)f2bf(v - bf2f(h));
        }
        a[kc]     = vh;
        a[8 + kc] = vl;
    }
}

// ---------------- t2[k] (np-exact) + eh bf16 rows ----------------
__global__ void t2_np_kernel(const float* __restrict__ embed, float* __restrict__ t2,
                             unsigned short* __restrict__ Eh) {
    int k = blockIdx.x * 256 + threadIdx.x;
    if (k >= K_EMB) return;
    const float* e = embed + (size_t)k * DIM;
    float p[256];
    for (int c = 0; c < DIM; c += 4) {
        float4 v = *(const float4*)(e + c);
        p[c]     = __fmul_rn(v.x, v.x);
        p[c + 1] = __fmul_rn(v.y, v.y);
        p[c + 2] = __fmul_rn(v.z, v.z);
        p[c + 3] = __fmul_rn(v.w, v.w);
    }
    t2[k] = np_pair256(p);
    unsigned short* dst = Eh + (size_t)k * DIM;
    for (int c0 = 0; c0 < DIM; c0 += 8) {
        short8 vh;
        #pragma unroll
        for (int u = 0; u < 8; ++u) vh[u] = (short)f2bf(e[c0 + u]);
        *(short8*)(dst + c0) = vh;
    }
}

// ---------------- MFMA fast pass: fused z-prep + top-2 + flags + z_q/loss/counts + one-hot ----------------
__launch_bounds__(256, 4)
__global__ void vq_mfma(const float* __restrict__ z,
                        const float* __restrict__ embed,
                        const unsigned short* __restrict__ Eh,
                        const float* __restrict__ t2g,
                        float* __restrict__ out,
                        unsigned int* __restrict__ nflag,
                        int* __restrict__ flags,
                        float* __restrict__ fbs,
                        unsigned int* __restrict__ counts,
                        float* __restrict__ loss_sum) {
    __shared__ unsigned short lds_b[32 * 264];        // 32 codes x 256 bf16, pad 8
    __shared__ float t2_lds[K_EMB];
    __shared__ int midx[64];

    const int tid  = threadIdx.x;
    const int lane = tid & 63;
    const int wv   = tid >> 6;
    const int l15  = lane & 15;
    const int quad = lane >> 4;
    const int m0   = blockIdx.x * 64;

    for (int i = tid; i < K_EMB; i += 256) t2_lds[i] = t2g[i];

    short8 a[16];
    {
        const int n = m0 + wv * 16 + l15;
        build_frags(z + (size_t)(n >> 12) * CHW + (n & 4095), quad, a);
    }

    float bs[4], ss[4]; int bk[4];
    #pragma unroll
    for (int r = 0; r < 4; ++r) { bs[r] = 3.4e38f; ss[r] = 3.4e38f; bk[r] = 0; }

    const int srow = tid >> 3;
    const int scol = (tid & 7) * 32;

    for (int it = 0; it < 32; ++it) {
        const int n0 = it * 32;
        __syncthreads();
        {
            const short8* g = (const short8*)(Eh + (size_t)(n0 + srow) * 256 + scol);
            short8* l = (short8*)(lds_b + srow * 264 + scol);
            short8 v0 = g[0], v1 = g[1], v2 = g[2], v3 = g[3];
            l[0] = v0; l[1] = v1; l[2] = v2; l[3] = v3;
        }
        __syncthreads();
        floatx4 acc0 = {0.f, 0.f, 0.f, 0.f};
        floatx4 acc1 = {0.f, 0.f, 0.f, 0.f};
        #pragma unroll
        for (int kc = 0; kc < 8; ++kc) {
            short8 b0 = *(const short8*)(lds_b + l15 * 264 + kc * 32 + quad * 8);
            short8 b1 = *(const short8*)(lds_b + (16 + l15) * 264 + kc * 32 + quad * 8);
            acc0 = __builtin_amdgcn_mfma_f32_16x16x32_bf16(a[kc],     b0, acc0, 0, 0, 0);
            acc1 = __builtin_amdgcn_mfma_f32_16x16x32_bf16(a[kc],     b1, acc1, 0, 0, 0);
            acc0 = __builtin_amdgcn_mfma_f32_16x16x32_bf16(a[8 + kc], b0, acc0, 0, 0, 0);
            acc1 = __builtin_amdgcn_mfma_f32_16x16x32_bf16(a[8 + kc], b1, acc1, 0, 0, 0);
        }
        float t20 = t2_lds[n0 + l15];
        float t21 = t2_lds[n0 + 16 + l15];
        #pragma unroll
        for (int r = 0; r < 4; ++r) {
            float s0 = fmaf(-2.0f, acc0[r], t20);
            if (s0 < bs[r]) { ss[r] = bs[r]; bs[r] = s0; bk[r] = n0 + l15; }
            else if (s0 < ss[r]) ss[r] = s0;
            float s1 = fmaf(-2.0f, acc1[r], t21);
            if (s1 < bs[r]) { ss[r] = bs[r]; bs[r] = s1; bk[r] = n0 + 16 + l15; }
            else if (s1 < ss[r]) ss[r] = s1;
        }
    }

    // merge top-2 across the 16 lanes of each quad (token = wv*16 + quad*4 + r)
    #pragma unroll
    for (int r = 0; r < 4; ++r) {
        for (int mo = 1; mo < 16; mo <<= 1) {
            float obs = __shfl_xor(bs[r], mo, 64);
            float oss = __shfl_xor(ss[r], mo, 64);
            int   obk = __shfl_xor(bk[r], mo, 64);
            if (obs < bs[r] || (obs == bs[r] && obk < bk[r])) {
                ss[r] = fminf(bs[r], oss); bs[r] = obs; bk[r] = obk;
            } else {
                ss[r] = fminf(ss[r], obs);
            }
        }
        if (l15 == 0) {
            int tl = wv * 16 + quad * 4 + r;
            out[OUT_IDX + m0 + tl] = (float)bk[r];
            midx[tl] = bk[r];
            atomicAdd(&counts[bk[r]], 1u);
            if (ss[r] - bs[r] < TAU) {
                unsigned int slot = atomicAdd(nflag, 1u);
                flags[slot] = m0 + tl;
                fbs[slot]   = bs[r];
            }
        }
    }
    __syncthreads();   // midx visible to all

    // ---- fused z_q gather + loss: this thread's token = m0 + wv*16 + l15 ----
    {
        const int n   = m0 + wv * 16 + l15;
        const int myk = midx[wv * 16 + l15];
        const float* erow = embed + (size_t)myk * DIM;
        float* zqp = out + OUT_ZQ + (size_t)(n >> 12) * CHW + (n & 4095);
        float lsum = 0.0f;
        #pragma unroll
        for (int kc = 0; kc < 8; ++kc) {
            const int c0 = kc * 32 + quad * 8;
            float4 e0 = *(const float4*)(erow + c0);
            float4 e1 = *(const float4*)(erow + c0 + 4);
            float ev[8] = {e0.x, e0.y, e0.z, e0.w, e1.x, e1.y, e1.z, e1.w};
            #pragma unroll
            for (int u = 0; u < 8; ++u) {
                float vv = __fadd_rn(bf2f((unsigned short)a[kc][u]),
                                     bf2f((unsigned short)a[8 + kc][u]));
                float dz = ev[u] - vv;
                lsum = fmaf(dz, dz, lsum);
                __builtin_nontemporal_store(ev[u], zqp + (size_t)(c0 + u) * HW);
            }
        }
        #pragma unroll
        for (int off = 32; off > 0; off >>= 1) lsum += __shfl_down(lsum, off, 64);
        if (lane == 0) atomicAdd(loss_sum, lsum);
    }

    // provisional one-hot rows (non-temporal). Tail rows written later by menc_tail.
    if (blockIdx.x < (TAIL_ROW0 / 64)) {
        #pragma unroll 1
        for (int j = 0; j < 64; ++j) {
            const int id = midx[j];
            floatx2* dst = (floatx2*)(out + OUT_MENC + (size_t)(m0 + j) * K_EMB);
            int c0 = tid * 2;
            floatx2 v;  v.x  = (c0 == id)       ? 1.0f : 0.0f;  v.y  = (c0 + 1 == id)  ? 1.0f : 0.0f;
            __builtin_nontemporal_store(v, dst + tid);
            int c1 = c0 + 512;
            floatx2 w2; w2.x = (c1 == id)       ? 1.0f : 0.0f;  w2.y = (c1 + 1 == id)  ? 1.0f : 0.0f;
            __builtin_nontemporal_store(w2, dst + 256 + tid);
        }
    }
}

// ---------------- refine: recompute MFMA scores for flagged tokens (bit-identical),
// window TAU -> candidates -> np-exact fp64 check -> patch idx/one-hot/zq/loss/counts --------
__launch_bounds__(256)
__global__ void refine_mfma(const float* __restrict__ z, const float* __restrict__ embed,
                            const unsigned short* __restrict__ Eh,
                            const float* __restrict__ t2g, float* __restrict__ out,
                            const unsigned int* __restrict__ nflag,
                            const int* __restrict__ flags,
                            const float* __restrict__ fbs,
                            unsigned int* __restrict__ counts,
                            float* __restrict__ loss_sum) {
    __shared__ unsigned short lds_b[32 * 264];
    __shared__ float t2_lds[K_EMB];
    __shared__ int   ftok[64];
    __shared__ float fbest[64];
    __shared__ int   ccnt[64];
    __shared__ int   clist[64][32];
    __shared__ float pp4[4][256];

    const int tid  = threadIdx.x;
    const int lane = tid & 63;
    const int wv   = tid >> 6;
    const int l15  = lane & 15;
    const int quad = lane >> 4;
    const int nf   = (int)*nflag;

    for (int i = tid; i < K_EMB; i += 256) t2_lds[i] = t2g[i];

    const int srow = tid >> 3;
    const int scol = (tid & 7) * 32;

    for (int base = blockIdx.x * 64; base < nf; base += gridDim.x * 64) {
        __syncthreads();
        if (tid < 64) {
            int ii  = base + tid;
            int src = (ii < nf) ? ii : base;   // dup a valid token into empty slots
            ftok[tid]  = flags[src];
            fbest[tid] = fbs[src];
            ccnt[tid]  = 0;
        }
        __syncthreads();

        short8 a[16];
        {
            const int n = ftok[wv * 16 + l15];
            build_frags(z + (size_t)(n >> 12) * CHW + (n & 4095), quad, a);
        }
        float ftb[4];
        #pragma unroll
        for (int r = 0; r < 4; ++r) ftb[r] = fbest[wv * 16 + quad * 4 + r] + TAU;

        for (int it = 0; it < 32; ++it) {
            const int n0 = it * 32;
            __syncthreads();
            {
                const short8* g = (const short8*)(Eh + (size_t)(n0 + srow) * 256 + scol);
                short8* l = (short8*)(lds_b + srow * 264 + scol);
                short8 v0 = g[0], v1 = g[1], v2 = g[2], v3 = g[3];
                l[0] = v0; l[1] = v1; l[2] = v2; l[3] = v3;
            }
            __syncthreads();
            floatx4 acc0 = {0.f, 0.f, 0.f, 0.f};
            floatx4 acc1 = {0.f, 0.f, 0.f, 0.f};
            #pragma unroll
            for (int kc = 0; kc < 8; ++kc) {
                short8 b0 = *(const short8*)(lds_b + l15 * 264 + kc * 32 + quad * 8);
                short8 b1 = *(const short8*)(lds_b + (16 + l15) * 264 + kc * 32 + quad * 8);
                acc0 = __builtin_amdgcn_mfma_f32_16x16x32_bf16(a[kc],     b0, acc0, 0, 0, 0);
                acc1 = __builtin_amdgcn_mfma_f32_16x16x32_bf16(a[kc],     b1, acc1, 0, 0, 0);
                acc0 = __builtin_amdgcn_mfma_f32_16x16x32_bf16(a[8 + kc], b0, acc0, 0, 0, 0);
                acc1 = __builtin_amdgcn_mfma_f32_16x16x32_bf16(a[8 + kc], b1, acc1, 0, 0, 0);
            }
            float t20 = t2_lds[n0 + l15];
            float t21 = t2_lds[n0 + 16 + l15];
            #pragma unroll
            for (int r = 0; r < 4; ++r) {
                const int trow = wv * 16 + quad * 4 + r;
                float s0 = fmaf(-2.0f, acc0[r], t20);
                if (s0 <= ftb[r]) {
                    int pos = atomicAdd(&ccnt[trow], 1);
                    if (pos < 32) clist[trow][pos] = n0 + l15;
                }
                float s1 = fmaf(-2.0f, acc1[r], t21);
                if (s1 <= ftb[r]) {
                    int pos = atomicAdd(&ccnt[trow], 1);
                    if (pos < 32) clist[trow][pos] = n0 + 16 + l15;
                }
            }
        }
        __syncthreads();

        // exact np phase: wave wv owns token slots wv*16 .. wv*16+15
        for (int j = wv * 16; j < wv * 16 + 16; ++j) {
            if (base + j >= nf) break;
            const int n = ftok[j];
            int cnt = ccnt[j]; if (cnt > 32) cnt = 32;

            const float* zt = z + (size_t)(n >> 12) * CHW + (n & 4095);
            double zd[4]; float zf[4];
            #pragma unroll
            for (int u = 0; u < 4; ++u) {
                float v = zt[(size_t)(lane + u * 64) * HW];
                zf[u] = v; zd[u] = (double)v;
                pp4[wv][lane + u * 64] = __fmul_rn(v, v);
            }
            __asm__ volatile("s_waitcnt lgkmcnt(0)" ::: "memory");
            // numpy-pairwise t1: lanes 0..15 do the 8 strided accumulators per half
            float rj = 0.0f;
            if (lane < 16) {
                int jj = lane & 7, half = lane >> 3;
                const float* p = &pp4[wv][half * 128 + jj];
                rj = p[0];
                #pragma unroll
                for (int ii = 1; ii < 16; ++ii) rj = __fadd_rn(rj, p[ii * 8]);
            }
            float v0 = __shfl(rj, 0, 64), v1 = __shfl(rj, 1, 64), v2 = __shfl(rj, 2, 64), v3 = __shfl(rj, 3, 64);
            float v4 = __shfl(rj, 4, 64), v5 = __shfl(rj, 5, 64), v6 = __shfl(rj, 6, 64), v7 = __shfl(rj, 7, 64);
            float h0 = __fadd_rn(__fadd_rn(__fadd_rn(v0, v1), __fadd_rn(v2, v3)),
                                 __fadd_rn(__fadd_rn(v4, v5), __fadd_rn(v6, v7)));
            v0 = __shfl(rj,  8, 64); v1 = __shfl(rj,  9, 64); v2 = __shfl(rj, 10, 64); v3 = __shfl(rj, 11, 64);
            v4 = __shfl(rj, 12, 64); v5 = __shfl(rj, 13, 64); v6 = __shfl(rj, 14, 64); v7 = __shfl(rj, 15, 64);
            float h1 = __fadd_rn(__fadd_rn(__fadd_rn(v0, v1), __fadd_rn(v2, v3)),
                                 __fadd_rn(__fadd_rn(v4, v5), __fadd_rn(v6, v7)));
            const float t1 = __fadd_rn(h0, h1);

            float bd = 3.4e38f; int bkk = 1 << 30;
            for (int ci = 0; ci < cnt; ++ci) {
                int k = clist[j][ci];
                const float* e = embed + (size_t)k * DIM;
                double s = 0.0;
                #pragma unroll
                for (int u = 0; u < 4; ++u) s = fma(zd[u], (double)e[lane + u * 64], s);
                for (int mo = 1; mo < 64; mo <<= 1) s += __shfl_xor(s, mo, 64);
                float rho = (float)s;
                float d = __fadd_rn(__fadd_rn(t1, t2_lds[k]), -__fmul_rn(2.0f, rho));
                if (d < bd || (d == bd && k < bkk)) { bd = d; bkk = k; }
            }

            const int old = (int)out[OUT_IDX + n];
            if (bkk != old) {
                // patch zq row + loss delta (all 64 lanes, 4 elems each)
                const float* eo = embed + (size_t)old * DIM;
                const float* en = embed + (size_t)bkk * DIM;
                float* zqp = out + OUT_ZQ + (size_t)(n >> 12) * CHW + (n & 4095);
                float dl = 0.0f;
                #pragma unroll
                for (int u = 0; u < 4; ++u) {
                    const int c = lane + u * 64;
                    float d_new = en[c] - zf[u];
                    float d_old = eo[c] - zf[u];
                    dl += d_new * d_new - d_old * d_old;
                    zqp[(size_t)c * HW] = en[c];
                }
                for (int mo = 1; mo < 64; mo <<= 1) dl += __shfl_xor(dl, mo, 64);
                if (lane == 0) {
                    atomicAdd(loss_sum, dl);
                    atomicAdd(&counts[old], 0xFFFFFFFFu);   // -1
                    atomicAdd(&counts[bkk], 1u);
                    out[OUT_IDX + n] = (float)bkk;
                    if (n < TAIL_ROW0) {     // patch provisional one-hot row
                        out[OUT_MENC + (size_t)n * K_EMB + old] = 0.0f;
                        out[OUT_MENC + (size_t)n * K_EMB + bkk] = 1.0f;
                    }
                }
            }
        }
    }
}

// ---------------- tail one-hot rows (over the scratch region), after refine ----------------
__global__ void menc_tail(float* __restrict__ out) {
    const int row = TAIL_ROW0 + blockIdx.x;           // 320 rows
    const int id  = (int)out[OUT_IDX + row];
    floatx2* dst = (floatx2*)(out + OUT_MENC + (size_t)row * K_EMB);
    int c0 = threadIdx.x * 2;
    floatx2 v;  v.x  = (c0 == id)      ? 1.0f : 0.0f;  v.y  = (c0 + 1 == id) ? 1.0f : 0.0f;
    dst[threadIdx.x] = v;
    int c1 = c0 + 512;
    floatx2 w;  w.x  = (c1 == id)      ? 1.0f : 0.0f;  w.y  = (c1 + 1 == id) ? 1.0f : 0.0f;
    dst[256 + threadIdx.x] = w;
}

// ---------------- loss scale + perplexity ----------------
__global__ void finalize_kernel(const unsigned int* __restrict__ counts,
                                const float* __restrict__ loss_sum,
                                float* __restrict__ out) {
    __shared__ float red[256];
    int tid = threadIdx.x;
    float hsum = 0.0f;
    for (int k = tid; k < K_EMB; k += 256) {
        float p = (float)counts[k] * (1.0f / 65536.0f);
        hsum += p * logf(p + 1e-10f);
    }
    red[tid] = hsum;
    __syncthreads();
    for (int s = 128; s > 0; s >>= 1) {
        if (tid < s) red[tid] += red[tid + s];
        __syncthreads();
    }
    if (tid == 0) {
        out[OUT_PERP] = expf(-red[0]);
        out[OUT_LOSS] = loss_sum[0] * 1.25f * (1.0f / (float)NELEM);
    }
}

extern "C" void kernel_launch(void* const* d_in, const int* in_sizes, int n_in,
                              void* d_out, int out_size, void* d_ws, size_t ws_size,
                              hipStream_t stream) {
    const float* z     = (const float*)d_in[0];
    const float* embed = (const float*)d_in[1];
    float* out = (float*)d_out;

    unsigned int* counts = (unsigned int*)d_ws;                  // 1024 * u32
    float* loss_sum      = (float*)((char*)d_ws + 4096);
    unsigned int* nflag  = (unsigned int*)((char*)d_ws + 4100);
    float* t2g           = (float*)((char*)d_ws + 8192);         // 1024 floats

    float* scr = out + OUT_MENC;                                 // scratch in min_enc tail
    int*            fl = (int*)(scr + FLAGS_OFF);
    float*          fb = (float*)(scr + FBS_OFF);
    unsigned short* Eh = (unsigned short*)(scr + EH_OFF);

    (void)hipMemsetAsync(d_ws, 0, 4104, stream);
    t2_np_kernel   <<<dim3(4),    dim3(256), 0, stream>>>(embed, t2g, Eh);
    vq_mfma        <<<dim3(1024), dim3(256), 0, stream>>>(z, embed, Eh, t2g, out, nflag, fl, fb, counts, loss_sum);
    refine_mfma    <<<dim3(128),  dim3(256), 0, stream>>>(z, embed, Eh, t2g, out, nflag, fl, fb, counts, loss_sum);
    menc_tail      <<<dim3(320),  dim3(256), 0, stream>>>(out);
    finalize_kernel<<<dim3(1),    dim3(256), 0, stream>>>(counts, loss_sum, out);
}

// Round 5
// 726.504 us; speedup vs baseline: 1.0815x; 1.0655x over previous
//
#include <hip/hip_runtime.h>
#include <math.h>

#define DIM    256
#define K_EMB  1024
#define HW     4096
#define CHW    1048576
#define N_TOK  65536
#define NELEM  16777216

// d_out float offsets
#define OUT_LOSS 0
#define OUT_ZQ   1
#define OUT_PERP 16777217
#define OUT_MENC 16777218LL
#define OUT_IDX  83886082

#define TAU  1.5e-4f  // flag margin (proven): |s_mfma - s_np| <= TAU/2
#define CAND_CAP 16

// Only Eh scratch remains in the menc region: last 129 rows (written by menc_tail after vq).
#define TAIL_ROW0  65407
#define EH_OFF     66976770LL   // = 65407*1024 + 2  (≡2 mod 4 -> 16B-aligned abs addr)

typedef short short8  __attribute__((ext_vector_type(8)));
typedef float floatx4 __attribute__((ext_vector_type(4)));
typedef float floatx2 __attribute__((ext_vector_type(2)));

__device__ __forceinline__ unsigned short f2bf(float f) {  // RNE fp32->bf16
    unsigned int u = __float_as_uint(f);
    return (unsigned short)((u + 0x7FFFu + ((u >> 16) & 1u)) >> 16);
}
__device__ __forceinline__ float bf2f(unsigned short h) {
    return __uint_as_float(((unsigned int)h) << 16);
}

// ---- numpy pairwise summation, exact replication for n=256 (serial form) ----
__device__ __forceinline__ float np_pair128(const float* p) {
    float r[8];
    #pragma unroll
    for (int j = 0; j < 8; ++j) r[j] = p[j];
    for (int i = 8; i < 128; i += 8)
        #pragma unroll
        for (int j = 0; j < 8; ++j) r[j] = __fadd_rn(r[j], p[i + j]);
    return __fadd_rn(__fadd_rn(__fadd_rn(r[0], r[1]), __fadd_rn(r[2], r[3])),
                     __fadd_rn(__fadd_rn(r[4], r[5]), __fadd_rn(r[6], r[7])));
}
__device__ __forceinline__ float np_pair256(const float* p) {
    return __fadd_rn(np_pair128(p), np_pair128(p + 128));
}

// fused prep: one token's z row -> bf16 split fragments
__device__ __forceinline__ void build_frags(const float* __restrict__ zp, int quad, short8* a) {
    #pragma unroll
    for (int kc = 0; kc < 8; ++kc) {
        short8 vh, vl;
        #pragma unroll
        for (int u = 0; u < 8; ++u) {
            float v = __builtin_nontemporal_load(zp + (size_t)(kc * 32 + quad * 8 + u) * HW);
            unsigned short h = f2bf(v);
            vh[u] = (short)h;
            vl[u] = (short)f2bf(v - bf2f(h));
        }
        a[kc]     = vh;
        a[8 + kc] = vl;
    }
}

// ---------------- t2[k] (np-exact) + eh bf16 rows ----------------
__global__ void t2_np_kernel(const float* __restrict__ embed, float* __restrict__ t2,
                             unsigned short* __restrict__ Eh) {
    int k = blockIdx.x * 256 + threadIdx.x;
    if (k >= K_EMB) return;
    const float* e = embed + (size_t)k * DIM;
    float p[256];
    for (int c = 0; c < DIM; c += 4) {
        float4 v = *(const float4*)(e + c);
        p[c]     = __fmul_rn(v.x, v.x);
        p[c + 1] = __fmul_rn(v.y, v.y);
        p[c + 2] = __fmul_rn(v.z, v.z);
        p[c + 3] = __fmul_rn(v.w, v.w);
    }
    t2[k] = np_pair256(p);
    unsigned short* dst = Eh + (size_t)k * DIM;
    for (int c0 = 0; c0 < DIM; c0 += 8) {
        short8 vh;
        #pragma unroll
        for (int u = 0; u < 8; ++u) vh[u] = (short)f2bf(e[c0 + u]);
        *(short8*)(dst + c0) = vh;
    }
}

// ---------------- MFMA pass: z-prep + top-2 + in-loop candidate capture +
// in-block np-exact refine + idx/counts/zq/loss/one-hot ----------------
__launch_bounds__(256, 4)
__global__ void vq_mfma(const float* __restrict__ z,
                        const float* __restrict__ embed,
                        const unsigned short* __restrict__ Eh,
                        const float* __restrict__ t2g,
                        float* __restrict__ out,
                        unsigned int* __restrict__ counts,
                        float* __restrict__ loss_sum) {
    __shared__ unsigned short lds_b[32 * 264];        // 32 codes x 256 bf16, pad 8
    __shared__ float t2_lds[K_EMB];
    __shared__ int midx[64];
    __shared__ unsigned short clist[64][CAND_CAP];
    __shared__ int ccnt[64];
    __shared__ int flist[64];
    __shared__ int fn;
    __shared__ float pp4[4][256];

    const int tid  = threadIdx.x;
    const int lane = tid & 63;
    const int wv   = tid >> 6;
    const int l15  = lane & 15;
    const int quad = lane >> 4;
    const int m0   = blockIdx.x * 64;

    for (int i = tid; i < K_EMB; i += 256) t2_lds[i] = t2g[i];
    if (tid < 64) ccnt[tid] = 0;
    if (tid == 0) fn = 0;

    short8 a[16];
    {
        const int n = m0 + wv * 16 + l15;
        build_frags(z + (size_t)(n >> 12) * CHW + (n & 4095), quad, a);
    }

    float bs[4], ss[4], tb[4]; int bk[4];
    #pragma unroll
    for (int r = 0; r < 4; ++r) { bs[r] = 3.4e38f; ss[r] = 3.4e38f; tb[r] = 3.4e38f; bk[r] = 0; }

    const int srow = tid >> 3;
    const int scol = (tid & 7) * 32;

    for (int it = 0; it < 32; ++it) {
        const int n0 = it * 32;
        __syncthreads();
        {
            const short8* g = (const short8*)(Eh + (size_t)(n0 + srow) * 256 + scol);
            short8* l = (short8*)(lds_b + srow * 264 + scol);
            short8 v0 = g[0], v1 = g[1], v2 = g[2], v3 = g[3];
            l[0] = v0; l[1] = v1; l[2] = v2; l[3] = v3;
        }
        __syncthreads();
        floatx4 acc0 = {0.f, 0.f, 0.f, 0.f};
        floatx4 acc1 = {0.f, 0.f, 0.f, 0.f};
        #pragma unroll
        for (int kc = 0; kc < 8; ++kc) {
            short8 b0 = *(const short8*)(lds_b + l15 * 264 + kc * 32 + quad * 8);
            short8 b1 = *(const short8*)(lds_b + (16 + l15) * 264 + kc * 32 + quad * 8);
            acc0 = __builtin_amdgcn_mfma_f32_16x16x32_bf16(a[kc],     b0, acc0, 0, 0, 0);
            acc1 = __builtin_amdgcn_mfma_f32_16x16x32_bf16(a[kc],     b1, acc1, 0, 0, 0);
            acc0 = __builtin_amdgcn_mfma_f32_16x16x32_bf16(a[8 + kc], b0, acc0, 0, 0, 0);
            acc1 = __builtin_amdgcn_mfma_f32_16x16x32_bf16(a[8 + kc], b1, acc1, 0, 0, 0);
        }
        float t20 = t2_lds[n0 + l15];
        float t21 = t2_lds[n0 + 16 + l15];
        #pragma unroll
        for (int r = 0; r < 4; ++r) {
            const int trow = wv * 16 + quad * 4 + r;
            float s0 = fmaf(-2.0f, acc0[r], t20);
            if (s0 < bs[r]) { ss[r] = bs[r]; bs[r] = s0; bk[r] = n0 + l15; }
            else if (s0 < ss[r]) ss[r] = s0;
            float s1 = fmaf(-2.0f, acc1[r], t21);
            if (s1 < bs[r]) { ss[r] = bs[r]; bs[r] = s1; bk[r] = n0 + 16 + l15; }
            else if (s1 < ss[r]) ss[r] = s1;

            // running token-global best (16-lane merge) + TAU-window candidate capture
            float m01 = fminf(s0, s1);
            #pragma unroll
            for (int mo = 1; mo < 16; mo <<= 1) m01 = fminf(m01, __shfl_xor(m01, mo, 64));
            tb[r] = fminf(tb[r], m01);
            const float thr = tb[r] + TAU;
            if (s0 <= thr) {
                int pos = atomicAdd(&ccnt[trow], 1);
                if (pos < CAND_CAP) clist[trow][pos] = (unsigned short)(n0 + l15);
            }
            if (s1 <= thr) {
                int pos = atomicAdd(&ccnt[trow], 1);
                if (pos < CAND_CAP) clist[trow][pos] = (unsigned short)(n0 + 16 + l15);
            }
        }
    }

    // merge top-2 across the 16 lanes of each quad (token = wv*16 + quad*4 + r)
    #pragma unroll
    for (int r = 0; r < 4; ++r) {
        for (int mo = 1; mo < 16; mo <<= 1) {
            float obs = __shfl_xor(bs[r], mo, 64);
            float oss = __shfl_xor(ss[r], mo, 64);
            int   obk = __shfl_xor(bk[r], mo, 64);
            if (obs < bs[r] || (obs == bs[r] && obk < bk[r])) {
                ss[r] = fminf(bs[r], oss); bs[r] = obs; bk[r] = obk;
            } else {
                ss[r] = fminf(ss[r], obs);
            }
        }
        if (l15 == 0) {
            int tl = wv * 16 + quad * 4 + r;
            midx[tl] = bk[r];
            if (ss[r] - bs[r] < TAU) {
                int p = atomicAdd(&fn, 1);
                flist[p] = tl;
            }
        }
    }
    __syncthreads();

    // ---- in-block np-exact refine of flagged tokens (one wave per token) ----
    const int nfb = fn;
    for (int f = wv; f < nfb; f += 4) {
        const int tl = flist[f];
        const int n  = m0 + tl;
        const int cnt = ccnt[tl];

        const float* zt = z + (size_t)(n >> 12) * CHW + (n & 4095);
        double zd[4];
        #pragma unroll
        for (int u = 0; u < 4; ++u) {
            float v = zt[(size_t)(lane + u * 64) * HW];
            zd[u] = (double)v;
            pp4[wv][lane + u * 64] = __fmul_rn(v, v);
        }
        __asm__ volatile("s_waitcnt lgkmcnt(0)" ::: "memory");
        // numpy-pairwise t1: lanes 0..15 do the 8 strided accumulators per half
        float rj = 0.0f;
        if (lane < 16) {
            int jj = lane & 7, half = lane >> 3;
            const float* p = &pp4[wv][half * 128 + jj];
            rj = p[0];
            #pragma unroll
            for (int ii = 1; ii < 16; ++ii) rj = __fadd_rn(rj, p[ii * 8]);
        }
        float v0 = __shfl(rj, 0, 64), v1 = __shfl(rj, 1, 64), v2 = __shfl(rj, 2, 64), v3 = __shfl(rj, 3, 64);
        float v4 = __shfl(rj, 4, 64), v5 = __shfl(rj, 5, 64), v6 = __shfl(rj, 6, 64), v7 = __shfl(rj, 7, 64);
        float h0 = __fadd_rn(__fadd_rn(__fadd_rn(v0, v1), __fadd_rn(v2, v3)),
                             __fadd_rn(__fadd_rn(v4, v5), __fadd_rn(v6, v7)));
        v0 = __shfl(rj,  8, 64); v1 = __shfl(rj,  9, 64); v2 = __shfl(rj, 10, 64); v3 = __shfl(rj, 11, 64);
        v4 = __shfl(rj, 12, 64); v5 = __shfl(rj, 13, 64); v6 = __shfl(rj, 14, 64); v7 = __shfl(rj, 15, 64);
        float h1 = __fadd_rn(__fadd_rn(__fadd_rn(v0, v1), __fadd_rn(v2, v3)),
                             __fadd_rn(__fadd_rn(v4, v5), __fadd_rn(v6, v7)));
        const float t1 = __fadd_rn(h0, h1);

        float bd = 3.4e38f; int bkk = 1 << 30;
        if (cnt <= CAND_CAP) {
            for (int ci = 0; ci < cnt; ++ci) {
                int k = clist[tl][ci];
                const float* e = embed + (size_t)k * DIM;
                double s = 0.0;
                #pragma unroll
                for (int u = 0; u < 4; ++u) s = fma(zd[u], (double)e[lane + u * 64], s);
                for (int mo = 1; mo < 64; mo <<= 1) s += __shfl_xor(s, mo, 64);
                float rho = (float)s;
                float d = __fadd_rn(__fadd_rn(t1, t2_lds[k]), -__fmul_rn(2.0f, rho));
                if (d < bd || (d == bd && k < bkk)) { bd = d; bkk = k; }
            }
        } else {   // overflow fallback: full np-exact scan (≈ never)
            for (int k = 0; k < K_EMB; ++k) {
                const float* e = embed + (size_t)k * DIM;
                double s = 0.0;
                #pragma unroll
                for (int u = 0; u < 4; ++u) s = fma(zd[u], (double)e[lane + u * 64], s);
                for (int mo = 1; mo < 64; mo <<= 1) s += __shfl_xor(s, mo, 64);
                float rho = (float)s;
                float d = __fadd_rn(__fadd_rn(t1, t2_lds[k]), -__fmul_rn(2.0f, rho));
                if (d < bd) { bd = d; bkk = k; }
            }
        }
        if (lane == 0) midx[tl] = bkk;
    }
    __syncthreads();

    // ---- epilogue: idx + counts (final midx) ----
    if (tid < 64) {
        const int id = midx[tid];
        out[OUT_IDX + m0 + tid] = (float)id;
        atomicAdd(&counts[id], 1u);
    }

    // ---- fused z_q gather + loss: this thread's token = m0 + wv*16 + l15 ----
    {
        const int n   = m0 + wv * 16 + l15;
        const int myk = midx[wv * 16 + l15];
        const float* erow = embed + (size_t)myk * DIM;
        float* zqp = out + OUT_ZQ + (size_t)(n >> 12) * CHW + (n & 4095);
        float lsum = 0.0f;
        #pragma unroll
        for (int kc = 0; kc < 8; ++kc) {
            const int c0 = kc * 32 + quad * 8;
            float4 e0 = *(const float4*)(erow + c0);
            float4 e1 = *(const float4*)(erow + c0 + 4);
            float ev[8] = {e0.x, e0.y, e0.z, e0.w, e1.x, e1.y, e1.z, e1.w};
            #pragma unroll
            for (int u = 0; u < 8; ++u) {
                float vv = __fadd_rn(bf2f((unsigned short)a[kc][u]),
                                     bf2f((unsigned short)a[8 + kc][u]));
                float dz = ev[u] - vv;
                lsum = fmaf(dz, dz, lsum);
                __builtin_nontemporal_store(ev[u], zqp + (size_t)(c0 + u) * HW);
            }
        }
        #pragma unroll
        for (int off = 32; off > 0; off >>= 1) lsum += __shfl_down(lsum, off, 64);
        if (lane == 0) atomicAdd(loss_sum, lsum);
    }

    // ---- one-hot rows (non-temporal). Tail rows (Eh scratch) written by menc_tail. ----
    #pragma unroll 1
    for (int j = 0; j < 64; ++j) {
        if (m0 + j >= TAIL_ROW0) break;
        const int id = midx[j];
        floatx2* dst = (floatx2*)(out + OUT_MENC + (size_t)(m0 + j) * K_EMB);
        int c0 = tid * 2;
        floatx2 v;  v.x  = (c0 == id)       ? 1.0f : 0.0f;  v.y  = (c0 + 1 == id)  ? 1.0f : 0.0f;
        __builtin_nontemporal_store(v, dst + tid);
        int c1 = c0 + 512;
        floatx2 w2; w2.x = (c1 == id)       ? 1.0f : 0.0f;  w2.y = (c1 + 1 == id)  ? 1.0f : 0.0f;
        __builtin_nontemporal_store(w2, dst + 256 + tid);
    }
}

// ---------------- tail one-hot rows (over the Eh scratch region), after vq ----------------
__global__ void menc_tail(float* __restrict__ out) {
    const int row = TAIL_ROW0 + blockIdx.x;           // 129 rows
    const int id  = (int)out[OUT_IDX + row];
    floatx2* dst = (floatx2*)(out + OUT_MENC + (size_t)row * K_EMB);
    int c0 = threadIdx.x * 2;
    floatx2 v;  v.x  = (c0 == id)      ? 1.0f : 0.0f;  v.y  = (c0 + 1 == id) ? 1.0f : 0.0f;
    dst[threadIdx.x] = v;
    int c1 = c0 + 512;
    floatx2 w;  w.x  = (c1 == id)      ? 1.0f : 0.0f;  w.y  = (c1 + 1 == id) ? 1.0f : 0.0f;
    dst[256 + threadIdx.x] = w;
}

// ---------------- loss scale + perplexity ----------------
__global__ void finalize_kernel(const unsigned int* __restrict__ counts,
                                const float* __restrict__ loss_sum,
                                float* __restrict__ out) {
    __shared__ float red[256];
    int tid = threadIdx.x;
    float hsum = 0.0f;
    for (int k = tid; k < K_EMB; k += 256) {
        float p = (float)counts[k] * (1.0f / 65536.0f);
        hsum += p * logf(p + 1e-10f);
    }
    red[tid] = hsum;
    __syncthreads();
    for (int s = 128; s > 0; s >>= 1) {
        if (tid < s) red[tid] += red[tid + s];
        __syncthreads();
    }
    if (tid == 0) {
        out[OUT_PERP] = expf(-red[0]);
        out[OUT_LOSS] = loss_sum[0] * 1.25f * (1.0f / (float)NELEM);
    }
}

extern "C" void kernel_launch(void* const* d_in, const int* in_sizes, int n_in,
                              void* d_out, int out_size, void* d_ws, size_t ws_size,
                              hipStream_t stream) {
    const float* z     = (const float*)d_in[0];
    const float* embed = (const float*)d_in[1];
    float* out = (float*)d_out;

    unsigned int* counts = (unsigned int*)d_ws;                  // 1024 * u32
    float* loss_sum      = (float*)((char*)d_ws + 4096);
    float* t2g           = (float*)((char*)d_ws + 8192);         // 1024 floats

    float* scr = out + OUT_MENC;                                 // Eh scratch in menc tail
    unsigned short* Eh = (unsigned short*)(scr + EH_OFF);

    (void)hipMemsetAsync(d_ws, 0, 4104, stream);
    t2_np_kernel   <<<dim3(4),    dim3(256), 0, stream>>>(embed, t2g, Eh);
    vq_mfma        <<<dim3(1024), dim3(256), 0, stream>>>(z, embed, Eh, t2g, out, counts, loss_sum);
    menc_tail      <<<dim3(129),  dim3(256), 0, stream>>>(out);
    finalize_kernel<<<dim3(1),    dim3(256), 0, stream>>>(counts, loss_sum, out);
}